// Round 10
// baseline (188.760 us; speedup 1.0000x reference)
//
#include <hip/hip_runtime.h>

// Problem: B=2, T=2048, D=1024, H=16, dh=64. All inputs/outputs fp32.
// Pipeline (bf16 MFMA internally):
//   cvt_all: x,w_qkv,w_proj -> bf16
//   gemm_qkv: qkvb [t][3072] (q cols pre-scaled by 0.125*log2e). BK=64+swizzle.
//   attn_mfma: R8 dbuf + V-transpose-in-staging; P C->A layout transform done
//              IN REGISTERS via v_permlane32_swap (no Ps LDS round-trip).
//   gemm_proj: out = attn @ w_proj^T (fp32 out). BK=64+swizzle.

typedef __attribute__((ext_vector_type(8))) short s8v;            // bf16 frag (4 VGPR)
typedef __attribute__((ext_vector_type(8))) unsigned short us8;   // 16B of bf16
typedef __attribute__((ext_vector_type(4))) unsigned short us4;   // 8B of bf16
typedef __attribute__((ext_vector_type(4))) float f4v;            // 16x16 C/D
typedef __attribute__((ext_vector_type(16))) float f16v;          // 32x32 C/D
typedef __attribute__((ext_vector_type(2))) unsigned u2v;

__device__ __forceinline__ unsigned short f2b(float f) {          // fp32->bf16 RNE
    unsigned u = __builtin_bit_cast(unsigned, f);
    u += 0x7FFFu + ((u >> 16) & 1u);
    return (unsigned short)(u >> 16);
}
// pack two positive floats to bf16x2 by truncation (1 v_perm_b32).
__device__ __forceinline__ unsigned packtrunc(float a, float b, unsigned sel) {
    unsigned r;
    asm("v_perm_b32 %0, %1, %2, %3"
        : "=v"(r)
        : "v"(__builtin_bit_cast(unsigned, b)), "v"(__builtin_bit_cast(unsigned, a)), "s"(sel));
    return r;
}

// (a,b) -> a' = {a.lower32lanes, b.lower32lanes}, b' = {a.upper, b.upper}
// i.e. swap a's upper lane-half with b's lower lane-half (gfx950 VALU op).
__device__ __forceinline__ void permswap32(unsigned& a, unsigned& b) {
#if __has_builtin(__builtin_amdgcn_permlane32_swap)
    u2v r = __builtin_amdgcn_permlane32_swap(a, b, false, false);
    a = r[0];
    b = r[1];
#else
    const int h2 = (threadIdx.x & 63) >> 5;
    unsigned pa = __shfl_xor(a, 32, 64), pb = __shfl_xor(b, 32, 64);
    unsigned na = h2 ? pb : a;
    unsigned nb = h2 ? b : pa;
    a = na;
    b = nb;
#endif
}

#if __has_builtin(__builtin_amdgcn_exp2f)
#define EXP2F(x) __builtin_amdgcn_exp2f(x)
#else
#define EXP2F(x) exp2f(x)
#endif

#define QSCALE 0.18033688011112042f   // 0.125 * log2(e)

// ---------------------------------------------------------------------------
__global__ __launch_bounds__(256) void cvt_all(const float* __restrict__ x,
                                               const float* __restrict__ wq,
                                               const float* __restrict__ wp,
                                               unsigned short* __restrict__ xb,
                                               unsigned short* __restrict__ wqb,
                                               unsigned short* __restrict__ wpb) {
    const int nx = 4096 * 1024 / 4, nq = 3072 * 1024 / 4;
    int i = blockIdx.x * 256 + threadIdx.x;
    const float* s;
    unsigned short* d;
    int j;
    if (i < nx)           { s = x;  d = xb;  j = i; }
    else if (i < nx + nq) { s = wq; d = wqb; j = i - nx; }
    else                  { s = wp; d = wpb; j = i - nx - nq; }
    float4 v = ((const float4*)s)[j];
    ushort4 o;
    o.x = f2b(v.x); o.y = f2b(v.y); o.z = f2b(v.z); o.w = f2b(v.w);
    ((ushort4*)d)[j] = o;
}

// ---------------------------------------------------------------------------
#define GLD_LDS16(g, l)                                                                        \
    __builtin_amdgcn_global_load_lds((const __attribute__((address_space(1))) unsigned*)(g),   \
                                     (__attribute__((address_space(3))) unsigned*)(l), 16, 0, 0)

// qkv GEMM: [4096,1024] x [3072,1024]^T -> qkvb [4096][3072] bf16,
// q cols (<1024) pre-scaled by QSCALE. BK=64, XOR chunk swizzle.
__global__ __launch_bounds__(256) void gemm_qkv(const unsigned short* __restrict__ A,
                                                const unsigned short* __restrict__ B,
                                                unsigned short* __restrict__ qkvb) {
    __shared__ unsigned short As[128][64];
    __shared__ unsigned short Bs[128][64];
    const int tid = threadIdx.x;
    const int l = tid & 63, w = tid >> 6;
    const int quad = l >> 4, ln = l & 15;
    const int m0 = blockIdx.y * 128, n0 = blockIdx.x * 128;
    const int wm = (w >> 1) * 64, wn = (w & 1) * 64;

    const f4v fz = {0.f, 0.f, 0.f, 0.f};
    f4v acc[4][4];
#pragma unroll
    for (int i = 0; i < 4; ++i)
#pragma unroll
        for (int j = 0; j < 4; ++j) acc[i][j] = fz;

    const int srow = tid >> 3, sc8 = tid & 7;
    const int gcol = ((sc8 ^ (srow & 7)) << 3);             // swizzled global col (shorts)
    const int koff0 = ((quad ^ (ln & 7)) << 3);
    const int koff1 = (((4 + quad) ^ (ln & 7)) << 3);

    for (int k0 = 0; k0 < 1024; k0 += 64) {
#pragma unroll
        for (int b = 0; b < 4; ++b) {
            GLD_LDS16(A + (size_t)(m0 + srow + 32 * b) * 1024 + k0 + gcol, &As[srow + 32 * b][sc8 * 8]);
            GLD_LDS16(B + (size_t)(n0 + srow + 32 * b) * 1024 + k0 + gcol, &Bs[srow + 32 * b][sc8 * 8]);
        }
        __syncthreads();
#pragma unroll
        for (int ks = 0; ks < 2; ++ks) {
            const int ko = ks ? koff1 : koff0;
            s8v af[4], bf[4];
#pragma unroll
            for (int mt = 0; mt < 4; ++mt) af[mt] = *(const s8v*)&As[wm + mt * 16 + ln][ko];
#pragma unroll
            for (int nt = 0; nt < 4; ++nt) bf[nt] = *(const s8v*)&Bs[wn + nt * 16 + ln][ko];
#pragma unroll
            for (int mt = 0; mt < 4; ++mt)
#pragma unroll
                for (int nt = 0; nt < 4; ++nt)
                    acc[mt][nt] = __builtin_amdgcn_mfma_f32_16x16x32_bf16(af[mt], bf[nt], acc[mt][nt], 0, 0, 0);
        }
        __syncthreads();
    }

#pragma unroll
    for (int mt = 0; mt < 4; ++mt)
#pragma unroll
        for (int nt = 0; nt < 4; ++nt) {
            const int col = n0 + wn + nt * 16 + ln;
            const int row = m0 + wm + mt * 16 + quad * 4;
            const float sc = (col < 1024) ? QSCALE : 1.0f;
#pragma unroll
            for (int r = 0; r < 4; ++r)
                qkvb[(size_t)(row + r) * 3072 + col] = f2b(acc[mt][nt][r] * sc);
        }
}

// ---------------------------------------------------------------------------
// proj GEMM: [4096,1024] x [1024,1024]^T -> fp32. 128x64 tiles, BK=64+swizzle.
__global__ __launch_bounds__(256) void gemm_proj(const unsigned short* __restrict__ A,
                                                 const unsigned short* __restrict__ B,
                                                 float* __restrict__ C) {
    __shared__ unsigned short As[128][64];
    __shared__ unsigned short Bs[64][64];
    const int tid = threadIdx.x;
    const int l = tid & 63, w = tid >> 6;
    const int quad = l >> 4, ln = l & 15;
    const int m0 = blockIdx.y * 128, n0 = blockIdx.x * 64;
    const int wm = w * 32;

    const f4v fz = {0.f, 0.f, 0.f, 0.f};
    f4v acc[2][4];
#pragma unroll
    for (int i = 0; i < 2; ++i)
#pragma unroll
        for (int j = 0; j < 4; ++j) acc[i][j] = fz;

    const int srow = tid >> 3, sc8 = tid & 7;
    const int gcol = ((sc8 ^ (srow & 7)) << 3);
    const int koff0 = ((quad ^ (ln & 7)) << 3);
    const int koff1 = (((4 + quad) ^ (ln & 7)) << 3);

    for (int k0 = 0; k0 < 1024; k0 += 64) {
#pragma unroll
        for (int b = 0; b < 4; ++b)
            GLD_LDS16(A + (size_t)(m0 + srow + 32 * b) * 1024 + k0 + gcol, &As[srow + 32 * b][sc8 * 8]);
#pragma unroll
        for (int b = 0; b < 2; ++b)
            GLD_LDS16(B + (size_t)(n0 + srow + 32 * b) * 1024 + k0 + gcol, &Bs[srow + 32 * b][sc8 * 8]);
        __syncthreads();
#pragma unroll
        for (int ks = 0; ks < 2; ++ks) {
            const int ko = ks ? koff1 : koff0;
            s8v af[2], bf[4];
#pragma unroll
            for (int mt = 0; mt < 2; ++mt) af[mt] = *(const s8v*)&As[wm + mt * 16 + ln][ko];
#pragma unroll
            for (int nt = 0; nt < 4; ++nt) bf[nt] = *(const s8v*)&Bs[nt * 16 + ln][ko];
#pragma unroll
            for (int mt = 0; mt < 2; ++mt)
#pragma unroll
                for (int nt = 0; nt < 4; ++nt)
                    acc[mt][nt] = __builtin_amdgcn_mfma_f32_16x16x32_bf16(af[mt], bf[nt], acc[mt][nt], 0, 0, 0);
        }
        __syncthreads();
    }

#pragma unroll
    for (int mt = 0; mt < 2; ++mt)
#pragma unroll
        for (int nt = 0; nt < 4; ++nt) {
            const int row = m0 + wm + mt * 16 + quad * 4;
            const int col = n0 + nt * 16 + ln;
#pragma unroll
            for (int r = 0; r < 4; ++r) C[(size_t)(row + r) * 1024 + col] = acc[mt][nt][r];
        }
}

// ---------------------------------------------------------------------------
// Flash attention, 32x32x16 MFMA. Block = 128 q x (h,b); 4 waves x 32 q.
// R8 double-buffer + single barrier/iter + V-transpose-in-staging.
// R10: P's C-layout -> A-layout transform done IN REGISTERS via
// v_permlane32_swap (lane l <-> l^32 exchange): lane (q=m31,h2) owns P at
// s ≡ 4h2..4h2+3 (mod 8); A-frag k2 needs s=16k2+8h2+{0..7} = own half +
// partner half. With X=U[k2>>1][(2k2)&3], Y=U[k2>>1][(2k2+1)&3]:
// permswap(X,Y) gives frag {X.x,X.y,Y.x,Y.y} uniformly for both halves.
// Replaces 8 ds_write_b64 + 4 ds_read_b128 per wave-iter with 8 VALU ops.
__global__ __launch_bounds__(256) void attn_mfma(const unsigned short* __restrict__ qkvb,
                                                 unsigned short* __restrict__ attnb) {
    __shared__ unsigned short Ks[2][64][76];   // [buf][s][d]
    __shared__ unsigned short Vt[2][64][76];   // [buf][d][s]
    __shared__ unsigned short Qs[128][76];     // prologue Q staging only
    __shared__ float lred[128];

    const int tid = threadIdx.x;
    const int l = tid & 63, w = tid >> 6;
    const int m31 = l & 31, h2 = l >> 5;
    const int qw = w * 32;
    const int t0 = blockIdx.x * 128;
    const int hh = blockIdx.y, bb = blockIdx.z;
    const size_t rowbase = (size_t)bb * 2048;
    const unsigned sel = 0x07060302u;

    // ---- prologue: stage Q coalesced -> LDS -> register frags ----
#pragma unroll
    for (int it = 0; it < 4; ++it) {
        const int idx = tid + it * 256;
        const int qr = idx >> 3, qc = (idx & 7) * 8;
        *(us8*)&Qs[qr][qc] = *(const us8*)(qkvb + (rowbase + t0 + qr) * 3072 + hh * 64 + qc);
    }
    __syncthreads();
    s8v qf[4];
#pragma unroll
    for (int k4 = 0; k4 < 4; ++k4)
        qf[k4] = *(const s8v*)&Qs[qw + m31][k4 * 16 + h2 * 8];

    // staging coords: K rows (b128), V 4-row x 4-col transpose chunks
    const int r0 = tid >> 3, c0 = (tid & 7) * 8;
    const int va = tid >> 4, vc = tid & 15;   // s-group 4*va, d-group 4*vc

    f16v zz;
#pragma unroll
    for (int i = 0; i < 16; ++i) zz[i] = 0.f;
    f16v oacc[2];
    oacc[0] = zz; oacc[1] = zz;
    float lsum = 0.f;

    // tile 0: global -> regs -> buf0
    us8 kreg0 = *(const us8*)(qkvb + (rowbase + r0) * 3072 + 1024 + hh * 64 + c0);
    us8 kreg1 = *(const us8*)(qkvb + (rowbase + r0 + 32) * 3072 + 1024 + hh * 64 + c0);
    us4 vreg[4];
#pragma unroll
    for (int j = 0; j < 4; ++j)
        vreg[j] = *(const us4*)(qkvb + (rowbase + 4 * va + j) * 3072 + 2048 + hh * 64 + 4 * vc);
    *(us8*)&Ks[0][r0][c0] = kreg0;
    *(us8*)&Ks[0][r0 + 32][c0] = kreg1;
#pragma unroll
    for (int dd = 0; dd < 4; ++dd) {
        unsigned lo = (unsigned)vreg[0][dd] | ((unsigned)vreg[1][dd] << 16);
        unsigned hi = (unsigned)vreg[2][dd] | ((unsigned)vreg[3][dd] << 16);
        uint2 pk2; pk2.x = lo; pk2.y = hi;
        *(uint2*)&Vt[0][4 * vc + dd][4 * va] = pk2;   // Vt[d][s0..s0+3]
    }

    for (int i = 0; i < 32; ++i) {
        const int cur = i & 1;
        __syncthreads();   // buf[cur] ready; prior reads of buf[1-cur] drained

        if (i + 1 < 32) {  // issue next tile's loads; compute body covers latency
            const int sn = (i + 1) * 64;
            kreg0 = *(const us8*)(qkvb + (rowbase + sn + r0) * 3072 + 1024 + hh * 64 + c0);
            kreg1 = *(const us8*)(qkvb + (rowbase + sn + r0 + 32) * 3072 + 1024 + hh * 64 + c0);
#pragma unroll
            for (int j = 0; j < 4; ++j)
                vreg[j] = *(const us4*)(qkvb + (rowbase + sn + 4 * va + j) * 3072 + 2048 + hh * 64 + 4 * vc);
        }

        // S^T[s][q] = K Q^T : A=K (m=s), B=Q (n=q), k=d
        f16v sacc[2];
        sacc[0] = zz; sacc[1] = zz;
#pragma unroll
        for (int k4 = 0; k4 < 4; ++k4) {
#pragma unroll
            for (int st = 0; st < 2; ++st) {
                s8v kf = *(const s8v*)&Ks[cur][st * 32 + m31][k4 * 16 + h2 * 8];
                sacc[st] = __builtin_amdgcn_mfma_f32_32x32x16_bf16(kf, qf[k4], sacc[st], 0, 0, 0);
            }
        }

        // p = 2^s (scale pre-folded into Q); truncating pack into registers.
        // C/D: col q = m31, row s = (reg&3) + 8*(reg>>2) + 4*h2 + 32*st
        unsigned U[2][4][2];
#pragma unroll
        for (int st = 0; st < 2; ++st)
#pragma unroll
            for (int g = 0; g < 4; ++g) {
                float p0 = EXP2F(sacc[st][g * 4 + 0]);
                float p1 = EXP2F(sacc[st][g * 4 + 1]);
                float p2 = EXP2F(sacc[st][g * 4 + 2]);
                float p3 = EXP2F(sacc[st][g * 4 + 3]);
                lsum += (p0 + p1) + (p2 + p3);
                U[st][g][0] = packtrunc(p0, p1, sel);
                U[st][g][1] = packtrunc(p2, p3, sel);
            }

        // O[q][d] += P V : assemble A-frags via permlane32_swap (in-register)
#pragma unroll
        for (int k2 = 0; k2 < 4; ++k2) {
            const int st = k2 >> 1, gA = (2 * k2) & 3, gB = (2 * k2 + 1) & 3;
            unsigned x0 = U[st][gA][0], x1 = U[st][gA][1];
            unsigned y0 = U[st][gB][0], y1 = U[st][gB][1];
            permswap32(x0, y0);
            permswap32(x1, y1);
            unsigned fr[4] = {x0, x1, y0, y1};
            s8v pf = *(const s8v*)fr;
#pragma unroll
            for (int nt = 0; nt < 2; ++nt) {
                s8v vfr = *(const s8v*)&Vt[cur][nt * 32 + m31][k2 * 16 + h2 * 8];
                oacc[nt] = __builtin_amdgcn_mfma_f32_32x32x16_bf16(pf, vfr, oacc[nt], 0, 0, 0);
            }
        }

        if (i + 1 < 32) {  // stage tile i+1 into the other buffer (tail; no barrier)
            *(us8*)&Ks[1 - cur][r0][c0] = kreg0;
            *(us8*)&Ks[1 - cur][r0 + 32][c0] = kreg1;
#pragma unroll
            for (int dd = 0; dd < 4; ++dd) {
                unsigned lo = (unsigned)vreg[0][dd] | ((unsigned)vreg[1][dd] << 16);
                unsigned hi = (unsigned)vreg[2][dd] | ((unsigned)vreg[3][dd] << 16);
                uint2 pk2; pk2.x = lo; pk2.y = hi;
                *(uint2*)&Vt[1 - cur][4 * vc + dd][4 * va] = pk2;
            }
        }
    }

    // l per query; 1.001955 = (1+2^-9) compensates the truncation bias in P
    lsum += __shfl_xor(lsum, 32, 64);
    lred[qw + m31] = lsum;
    __syncthreads();
    float inv[16];
#pragma unroll
    for (int g = 0; g < 4; ++g)
#pragma unroll
        for (int r = 0; r < 4; ++r)
            inv[g * 4 + r] = 1.001955f / lred[qw + 8 * g + 4 * h2 + r];

    // epilogue: O C/D layout col d = m31 (+32*nt), row q = 8g + 4h2 + r
#pragma unroll
    for (int nt = 0; nt < 2; ++nt)
#pragma unroll
        for (int g = 0; g < 4; ++g)
#pragma unroll
            for (int r = 0; r < 4; ++r) {
                const int qrow = 8 * g + 4 * h2 + r;
                float o = oacc[nt][g * 4 + r] * inv[g * 4 + r];
                attnb[(rowbase + t0 + qw + qrow) * 1024 + hh * 64 + nt * 32 + m31] = f2b(o);
            }
}

// ---------------------------------------------------------------------------
extern "C" void kernel_launch(void* const* d_in, const int* in_sizes, int n_in,
                              void* d_out, int out_size, void* d_ws, size_t ws_size,
                              hipStream_t stream) {
    const float* x      = (const float*)d_in[0];   // [4096,1024]
    const float* w_qkv  = (const float*)d_in[1];   // [3072,1024]
    const float* w_proj = (const float*)d_in[2];   // [1024,1024]
    float* out = (float*)d_out;

    char* p = (char*)d_ws;
    unsigned short* xb    = (unsigned short*)p;  p += (size_t)4096 * 1024 * 2;
    unsigned short* wqb   = (unsigned short*)p;  p += (size_t)3072 * 1024 * 2;
    unsigned short* wpb   = (unsigned short*)p;  p += (size_t)1024 * 1024 * 2;
    unsigned short* qkvb  = (unsigned short*)p;  p += (size_t)4096 * 3072 * 2;
    unsigned short* attnb = (unsigned short*)p;  p += (size_t)4096 * 1024 * 2;

    cvt_all<<<8192, 256, 0, stream>>>(x, w_qkv, w_proj, xb, wqb, wpb);

    gemm_qkv<<<dim3(3072 / 128, 4096 / 128), 256, 0, stream>>>(xb, wqb, qkvb);

    attn_mfma<<<dim3(2048 / 128, 16, 2), 256, 0, stream>>>(qkvb, attnb);

    gemm_proj<<<dim3(1024 / 64, 4096 / 128), 256, 0, stream>>>(attnb, wpb, out);
}